// Round 3
// baseline (39505.228 us; speedup 1.0000x reference)
//
#include <hip/hip_runtime.h>
#include <math.h>

#define H   512
#define B   512
#define T   512
#define TGT 28

typedef __bf16 bf16x8 __attribute__((ext_vector_type(8)));
typedef float  f32x4  __attribute__((ext_vector_type(4)));
typedef unsigned short u16;

// ws byte offsets
#define OFF_WPH  0x000000u  // Wpack_hi 2MB (frag-linear bf16)
#define OFF_WPL  0x200000u  // Wpack_lo 2MB
#define OFF_HHI0 0x400000u  // 512KB h hi buf0   (zeroed)
#define OFF_HLO0 0x480000u  // 512KB h lo buf0   (zeroed)
#define OFF_BAR  0x500000u  // 4KB barrier state (zeroed)
#define OFF_HHI1 0x501000u  // 512KB h hi buf1
#define OFF_HLO1 0x581000u  // 512KB h lo buf1

#define SMEM_BYTES (131072 + 64*65*4)   // W hi/lo (128KB) + gates[64][65] f32

__device__ inline u16 f2bf(float x) {
    unsigned u = __builtin_bit_cast(unsigned, x);
    u += 0x7FFFu + ((u >> 16) & 1u);
    return (u16)(u >> 16);
}
__device__ inline float bf2f(u16 h) {
    unsigned u = ((unsigned)h) << 16;
    return __builtin_bit_cast(float, u);
}

// ---------------------------------------------------------------------------
// Pack W_hh frag-linear bf16 hi/lo.  idx: by(5)|q(2)|S(4)|l(6), 8 k each.
// g = q*512 + by*16 + (l&15) ; k = S*32 + (l>>4)*8
// ---------------------------------------------------------------------------
__global__ __launch_bounds__(256) void init_pack(const float* __restrict__ Whh,
                                                 u16* __restrict__ wph,
                                                 u16* __restrict__ wpl) {
    int idx = blockIdx.x * 256 + threadIdx.x;   // [0, 131072)
    int l  = idx & 63;
    int S  = (idx >> 6) & 15;
    int q  = (idx >> 10) & 3;
    int by = idx >> 12;
    int g  = q * 512 + by * 16 + (l & 15);
    int k  = S * 32 + ((l >> 4) * 8);
    const float* src = Whh + (size_t)g * H + k;
    __align__(16) u16 hi8[8];
    __align__(16) u16 lo8[8];
#pragma unroll
    for (int j = 0; j < 8; ++j) {
        float w = src[j];
        u16 hb = f2bf(w);
        hi8[j] = hb;
        lo8[j] = f2bf(w - bf2f(hb));
    }
    *(uint4*)(wph + (size_t)idx * 8) = *(const uint4*)hi8;
    *(uint4*)(wpl + (size_t)idx * 8) = *(const uint4*)lo8;
}

// zero h buf0 (hi+lo) + barrier state: contiguous [OFF_HHI0, OFF_BAR+4K)
__global__ __launch_bounds__(256) void init_state(unsigned* __restrict__ zbase) {
    int idx = blockIdx.x * 256 + threadIdx.x;   // [0, 263168)
    if (idx < 263168) zbase[idx] = 0u;
}

// ---------------------------------------------------------------------------
// Persistent LSTM: 256 WGs x 512 thr, one per CU. WG=(bx,by): 64 batch rows,
// 16 h-cols (=64 gate rows). Waves: mt(2) x kh(4), K-split 4x128.
// W in LDS (loaded once); c, W_ih, bias in registers; h ping-pong in global.
// ---------------------------------------------------------------------------
__global__ __launch_bounds__(512, 2) void lstm_persistent(
    const u16* __restrict__ wph, const u16* __restrict__ wpl,
    u16* __restrict__ hhi0, u16* __restrict__ hlo0,
    u16* __restrict__ hhi1, u16* __restrict__ hlo1,
    int* __restrict__ bar,
    const float* __restrict__ seq, const float* __restrict__ Wih,
    const float* __restrict__ bih, const float* __restrict__ bhh)
{
    extern __shared__ char smem[];
    u16* wh = (u16*)smem;               // 32768 u16 (64KB)
    u16* wl = wh + 32768;               // 64KB
    float (*gates)[65] = (float(*)[65])(smem + 131072);

    const int tid  = threadIdx.x;
    const int l    = tid & 63;
    const int wave = tid >> 6;
    const int mt   = wave & 1;
    const int kh   = wave >> 1;
    const int wg   = blockIdx.x;
    const int bx   = wg & 7;
    const int by   = wg >> 3;

    // ---- stage W slice into LDS (once) ----
    {
        const uint4* gh = (const uint4*)(wph + (size_t)by * 32768);
        const uint4* gl = (const uint4*)(wpl + (size_t)by * 32768);
        uint4* sh = (uint4*)wh;
        uint4* sl = (uint4*)wl;
#pragma unroll
        for (int i = 0; i < 8; ++i) {
            int idx = tid + i * 512;    // 0..4095
            sh[idx] = gh[idx];
            sl[idx] = gl[idx];
        }
    }

    // ---- thread-resident cell constants ----
    const int cc   = tid & 15;
    const int m0   = tid >> 4;          // 0..31
    const int kcol = by * 16 + cc;
    float wib[4], bb[4];
#pragma unroll
    for (int q = 0; q < 4; ++q) {
        int g = q * 512 + kcol;
        wib[q] = Wih[g];
        bb[q]  = bih[g] + bhh[g];
    }
    float cr0 = 0.0f, cr1 = 0.0f;
    const int b0 = bx * 64 + m0;
    const int b1 = b0 + 32;

    const int arow0 = (bx * 64 + mt * 32 + (l & 15)) * H;
    const int arow1 = arow0 + 16 * H;

    __syncthreads();                    // W staged

    for (int t = 0; t < T; ++t) {
        const u16* hih = (t & 1) ? hhi1 : hhi0;
        const u16* hil = (t & 1) ? hlo1 : hlo0;
        u16* hoh = (t & 1) ? hhi0 : hhi1;
        u16* hol = (t & 1) ? hlo0 : hlo1;

        f32x4 acc[2][4] = {};

#pragma unroll
        for (int s = 0; s < 4; ++s) {
            const int S  = kh * 4 + s;
            const int ka = S * 32 + ((l >> 4) * 8);
            bf16x8 a0h = *(const bf16x8*)(hih + arow0 + ka);
            bf16x8 a1h = *(const bf16x8*)(hih + arow1 + ka);
            bf16x8 a0l = *(const bf16x8*)(hil + arow0 + ka);
            bf16x8 a1l = *(const bf16x8*)(hil + arow1 + ka);
#pragma unroll
            for (int n = 0; n < 4; ++n) {
                const int fo = ((n * 16 + S) * 64 + l) * 8;
                bf16x8 bh = *(const bf16x8*)(wh + fo);
                bf16x8 bl = *(const bf16x8*)(wl + fo);
                acc[0][n] = __builtin_amdgcn_mfma_f32_16x16x32_bf16(a0h, bh, acc[0][n], 0, 0, 0);
                acc[1][n] = __builtin_amdgcn_mfma_f32_16x16x32_bf16(a1h, bh, acc[1][n], 0, 0, 0);
                acc[0][n] = __builtin_amdgcn_mfma_f32_16x16x32_bf16(a0h, bl, acc[0][n], 0, 0, 0);
                acc[1][n] = __builtin_amdgcn_mfma_f32_16x16x32_bf16(a1h, bl, acc[1][n], 0, 0, 0);
                acc[0][n] = __builtin_amdgcn_mfma_f32_16x16x32_bf16(a0l, bh, acc[0][n], 0, 0, 0);
                acc[1][n] = __builtin_amdgcn_mfma_f32_16x16x32_bf16(a1l, bh, acc[1][n], 0, 0, 0);
            }
        }

        // ---- K-split reduction through LDS (4 serialized rounds) ----
#pragma unroll
        for (int r = 0; r < 4; ++r) {
            if (kh == r) {
#pragma unroll
                for (int ms = 0; ms < 2; ++ms)
#pragma unroll
                    for (int n = 0; n < 4; ++n)
#pragma unroll
                        for (int reg = 0; reg < 4; ++reg) {
                            int m  = mt * 32 + ms * 16 + (l >> 4) * 4 + reg;
                            int n2 = n * 16 + (l & 15);
                            if (r == 0) gates[m][n2] = acc[ms][n][reg];
                            else        gates[m][n2] += acc[ms][n][reg];
                        }
            }
            __syncthreads();
        }

        // ---- cell update: 2 cells/thread, c in registers ----
        {
            float sv = seq[(size_t)b0 * T + t];
            float pre[4];
#pragma unroll
            for (int q = 0; q < 4; ++q) pre[q] = gates[m0][q * 16 + cc] + sv * wib[q] + bb[q];
            float ig = 1.0f / (1.0f + expf(-pre[0]));
            float fg = 1.0f / (1.0f + expf(-pre[1]));
            float gg = tanhf(pre[2]);
            float og = 1.0f / (1.0f + expf(-pre[3]));
            cr0 = fg * cr0 + ig * gg;
            float hv = og * tanhf(cr0);
            u16 hb = f2bf(hv);
            size_t ci = (size_t)b0 * H + kcol;
            hoh[ci] = hb;
            hol[ci] = f2bf(hv - bf2f(hb));
        }
        {
            float sv = seq[(size_t)b1 * T + t];
            float pre[4];
#pragma unroll
            for (int q = 0; q < 4; ++q) pre[q] = gates[m0 + 32][q * 16 + cc] + sv * wib[q] + bb[q];
            float ig = 1.0f / (1.0f + expf(-pre[0]));
            float fg = 1.0f / (1.0f + expf(-pre[1]));
            float gg = tanhf(pre[2]);
            float og = 1.0f / (1.0f + expf(-pre[3]));
            cr1 = fg * cr1 + ig * gg;
            float hv = og * tanhf(cr1);
            u16 hb = f2bf(hv);
            size_t ci = (size_t)b1 * H + kcol;
            hoh[ci] = hb;
            hol[ci] = f2bf(hv - bf2f(hb));
        }

        // ---- grid barrier: release fence, tree arrive, spin, acquire fence ----
        __threadfence();
        __syncthreads();
        if (tid == 0) {
            int g = wg & 15;                      // 16 groups of 16 WGs
            int old = __hip_atomic_fetch_add(&bar[g * 32], 1,
                                             __ATOMIC_RELAXED, __HIP_MEMORY_SCOPE_AGENT);
            if (old == 16 * (t + 1) - 1) {
                int ro = __hip_atomic_fetch_add(&bar[512], 1,
                                                __ATOMIC_RELAXED, __HIP_MEMORY_SCOPE_AGENT);
                if (ro == 16 * (t + 1) - 1)
                    __hip_atomic_store(&bar[544], t + 1,
                                       __ATOMIC_RELAXED, __HIP_MEMORY_SCOPE_AGENT);
            }
            while (__hip_atomic_load(&bar[544], __ATOMIC_RELAXED,
                                     __HIP_MEMORY_SCOPE_AGENT) < t + 1)
                __builtin_amdgcn_s_sleep(1);
        }
        __syncthreads();
        __threadfence();
    }
}

// ---------------------------------------------------------------------------
// MLP head
// ---------------------------------------------------------------------------
__global__ __launch_bounds__(256) void head_kernel(const u16* __restrict__ hhi,
                                                   const u16* __restrict__ hlo,
                                                   const float* __restrict__ fc1w,
                                                   const float* __restrict__ fc1b,
                                                   const float* __restrict__ fc2w,
                                                   const float* __restrict__ fc2b,
                                                   float* __restrict__ out) {
    const int b = blockIdx.x;
    const int tid = threadIdx.x;
    __shared__ __align__(16) float hb[H];
    __shared__ float z[256];

    hb[tid]       = bf2f(hhi[(size_t)b * H + tid])       + bf2f(hlo[(size_t)b * H + tid]);
    hb[tid + 256] = bf2f(hhi[(size_t)b * H + tid + 256]) + bf2f(hlo[(size_t)b * H + tid + 256]);
    __syncthreads();

    float acc = fc1b[tid];
    const float4* wr = (const float4*)(fc1w + (size_t)tid * H);
    const float4* hr = (const float4*)hb;
#pragma unroll 4
    for (int kk = 0; kk < H / 4; ++kk) {
        float4 wv = wr[kk], hv = hr[kk];
        acc += wv.x * hv.x + wv.y * hv.y + wv.z * hv.z + wv.w * hv.w;
    }
    z[tid] = fmaxf(acc, 0.0f);
    __syncthreads();

    if (tid < TGT) {
        float a = fc2b[tid];
        const float* w2 = fc2w + (size_t)tid * 256;
#pragma unroll 8
        for (int j = 0; j < 256; ++j) a += z[j] * w2[j];
        out[(size_t)b * TGT + tid] = a;
    }
}

extern "C" void kernel_launch(void* const* d_in, const int* in_sizes, int n_in,
                              void* d_out, int out_size, void* d_ws, size_t ws_size,
                              hipStream_t stream) {
    const float* seq  = (const float*)d_in[0];
    const float* Wih  = (const float*)d_in[1];
    const float* Whh  = (const float*)d_in[2];
    const float* bih  = (const float*)d_in[3];
    const float* bhh  = (const float*)d_in[4];
    const float* fc1w = (const float*)d_in[5];
    const float* fc1b = (const float*)d_in[6];
    const float* fc2w = (const float*)d_in[7];
    const float* fc2b = (const float*)d_in[8];
    float* out = (float*)d_out;

    char* wsb = (char*)d_ws;
    u16* wph  = (u16*)(wsb + OFF_WPH);
    u16* wpl  = (u16*)(wsb + OFF_WPL);
    u16* hhi0 = (u16*)(wsb + OFF_HHI0);
    u16* hlo0 = (u16*)(wsb + OFF_HLO0);
    u16* hhi1 = (u16*)(wsb + OFF_HHI1);
    u16* hlo1 = (u16*)(wsb + OFF_HLO1);
    int* bar  = (int*)(wsb + OFF_BAR);

    init_pack<<<512, 256, 0, stream>>>(Whh, wph, wpl);
    init_state<<<1028, 256, 0, stream>>>((unsigned*)(wsb + OFF_HHI0));

    static int attr_done = 0;
    hipFuncSetAttribute((const void*)lstm_persistent,
                        hipFuncAttributeMaxDynamicSharedMemorySize, SMEM_BYTES);
    (void)attr_done;

    void* args[] = {(void*)&wph, (void*)&wpl, (void*)&hhi0, (void*)&hlo0,
                    (void*)&hhi1, (void*)&hlo1, (void*)&bar, (void*)&seq,
                    (void*)&Wih, (void*)&bih, (void*)&bhh};
    hipLaunchCooperativeKernel((const void*)lstm_persistent, dim3(256), dim3(512),
                               args, SMEM_BYTES, stream);

    // T even -> final h in buffer 0
    head_kernel<<<B, 256, 0, stream>>>(hhi0, hlo0, fc1w, fc1b, fc2w, fc2b, out);
}

// Round 4
// 6036.258 us; speedup vs baseline: 6.5447x; 6.5447x over previous
//
#include <hip/hip_runtime.h>
#include <math.h>

#define H   512
#define B   512
#define T   512
#define TGT 28

typedef __bf16 bf16x8 __attribute__((ext_vector_type(8)));
typedef float  f32x4  __attribute__((ext_vector_type(4)));
typedef unsigned short u16;

// ws byte offsets
#define OFF_WPH  0x000000u  // Wpack_hi 2MB (frag-linear bf16)
#define OFF_WPL  0x200000u  // Wpack_lo 2MB
#define OFF_HHI0 0x400000u  // 512KB h hi buf0   (zeroed)
#define OFF_HLO0 0x480000u  // 512KB h lo buf0   (zeroed)
#define OFF_C    0x500000u  // 1MB   c fp32      (zeroed)
#define OFF_HHI1 0x600000u  // 512KB h hi buf1
#define OFF_HLO1 0x680000u  // 512KB h lo buf1
#define OFF_BIAS 0x700000u  // 8KB   b_ih + b_hh fp32

__device__ inline u16 f2bf(float x) {
    unsigned u = __builtin_bit_cast(unsigned, x);
    u += 0x7FFFu + ((u >> 16) & 1u);          // RNE
    return (u16)(u >> 16);
}
__device__ inline float bf2f(u16 h) {
    unsigned u = ((unsigned)h) << 16;
    return __builtin_bit_cast(float, u);
}

// ---------------------------------------------------------------------------
// Pack W_hh frag-linear bf16 hi/lo.  idx: by(5)|q(2)|S(4)|l(6), 8 k each.
// g = q*512 + by*16 + (l&15) ; k = S*32 + (l>>4)*8
// ---------------------------------------------------------------------------
__global__ __launch_bounds__(256) void init_pack(const float* __restrict__ Whh,
                                                 u16* __restrict__ wph,
                                                 u16* __restrict__ wpl) {
    int idx = blockIdx.x * 256 + threadIdx.x;   // [0, 131072)
    int l  = idx & 63;
    int S  = (idx >> 6) & 15;
    int q  = (idx >> 10) & 3;
    int by = idx >> 12;
    int g  = q * 512 + by * 16 + (l & 15);
    int k  = S * 32 + ((l >> 4) * 8);
    const float* src = Whh + (size_t)g * H + k;
    __align__(16) u16 hi8[8];
    __align__(16) u16 lo8[8];
#pragma unroll
    for (int j = 0; j < 8; ++j) {
        float w = src[j];
        u16 hb = f2bf(w);
        hi8[j] = hb;
        lo8[j] = f2bf(w - bf2f(hb));
    }
    *(uint4*)(wph + (size_t)idx * 8) = *(const uint4*)hi8;
    *(uint4*)(wpl + (size_t)idx * 8) = *(const uint4*)lo8;
}

// zero h buf0 hi/lo + c (2MB contiguous from OFF_HHI0) and fill folded bias
__global__ __launch_bounds__(256) void init_state(unsigned* __restrict__ zbase,
                                                  float* __restrict__ bias,
                                                  const float* __restrict__ bih,
                                                  const float* __restrict__ bhh) {
    int idx = blockIdx.x * 256 + threadIdx.x;   // [0, 526336)
    if (idx < 524288) {
        zbase[idx] = 0u;
    } else {
        int g = idx - 524288;                   // [0, 2048)
        bias[g] = bih[g] + bhh[g];
    }
}

// ---------------------------------------------------------------------------
// One timestep. Grid (8,32) x 512 thr. WG: 64 batch x 16 h-cols (64 gate rows).
// Waves (mt,kh) = 2x4: wave tile 32b x 64g, K-split 4x128.
// A read once per WG (no dup); W mt-dup served by L1.
// bf16x3: Ahi*Bhi + Ahi*Blo + Alo*Bhi, fp32 accum.
// K-reduction: 2 LDS buffers, kh{0,1} write, kh{2,3} add, cell sums both.
// ---------------------------------------------------------------------------
__global__ __launch_bounds__(512) void lstm_step(
    const u16* __restrict__ wph, const u16* __restrict__ wpl,
    const u16* __restrict__ hih, const u16* __restrict__ hil,
    u16* __restrict__ hoh, u16* __restrict__ hol,
    float* __restrict__ cbuf, const float* __restrict__ bias,
    const float* __restrict__ Wih, const float* __restrict__ seq, int t)
{
    __shared__ float gates[2][64][67];

    const int tid  = threadIdx.x;
    const int l    = tid & 63;
    const int wave = tid >> 6;
    const int mt   = wave & 1;
    const int kh   = wave >> 1;          // 0..3
    const int bx   = blockIdx.x;         // 8 batch tiles
    const int by   = blockIdx.y;         // 32 col tiles

    f32x4 acc[2][4] = {};

    const int arow0 = (bx * 64 + mt * 32 + (l & 15)) * H;
    const int arow1 = arow0 + 16 * H;

#pragma unroll
    for (int s = 0; s < 4; ++s) {
        const int S  = kh * 4 + s;
        const int ka = S * 32 + ((l >> 4) * 8);
        bf16x8 a0h = *(const bf16x8*)(hih + arow0 + ka);
        bf16x8 a1h = *(const bf16x8*)(hih + arow1 + ka);
        bf16x8 a0l = *(const bf16x8*)(hil + arow0 + ka);
        bf16x8 a1l = *(const bf16x8*)(hil + arow1 + ka);
#pragma unroll
        for (int n = 0; n < 4; ++n) {
            const size_t fo = ((size_t)((by * 4 + n) * 16 + S) * 64 + l) * 8;
            bf16x8 bh = *(const bf16x8*)(wph + fo);
            bf16x8 bl = *(const bf16x8*)(wpl + fo);
            acc[0][n] = __builtin_amdgcn_mfma_f32_16x16x32_bf16(a0h, bh, acc[0][n], 0, 0, 0);
            acc[1][n] = __builtin_amdgcn_mfma_f32_16x16x32_bf16(a1h, bh, acc[1][n], 0, 0, 0);
            acc[0][n] = __builtin_amdgcn_mfma_f32_16x16x32_bf16(a0h, bl, acc[0][n], 0, 0, 0);
            acc[1][n] = __builtin_amdgcn_mfma_f32_16x16x32_bf16(a1h, bl, acc[1][n], 0, 0, 0);
            acc[0][n] = __builtin_amdgcn_mfma_f32_16x16x32_bf16(a0l, bh, acc[0][n], 0, 0, 0);
            acc[1][n] = __builtin_amdgcn_mfma_f32_16x16x32_bf16(a1l, bh, acc[1][n], 0, 0, 0);
        }
    }

    // ---- K reduction: D layout col=lane&15, row=(lane>>4)*4+reg ----
    if (kh < 2) {
#pragma unroll
        for (int ms = 0; ms < 2; ++ms)
#pragma unroll
            for (int n = 0; n < 4; ++n)
#pragma unroll
                for (int r = 0; r < 4; ++r)
                    gates[kh][mt * 32 + ms * 16 + (l >> 4) * 4 + r][n * 16 + (l & 15)]
                        = acc[ms][n][r];
    }
    __syncthreads();
    if (kh >= 2) {
#pragma unroll
        for (int ms = 0; ms < 2; ++ms)
#pragma unroll
            for (int n = 0; n < 4; ++n)
#pragma unroll
                for (int r = 0; r < 4; ++r)
                    gates[kh - 2][mt * 32 + ms * 16 + (l >> 4) * 4 + r][n * 16 + (l & 15)]
                        += acc[ms][n][r];
    }
    __syncthreads();

    // ---- cell update: 2 cells/thread ----
    const int cc   = tid & 15;
    const int m0   = tid >> 4;           // 0..31
    const int kcol = by * 16 + cc;
    float wib[4], bb[4];
#pragma unroll
    for (int q = 0; q < 4; ++q) {
        int g = q * 512 + kcol;
        wib[q] = Wih[g];
        bb[q]  = bias[g];
    }
#pragma unroll
    for (int mm = 0; mm < 2; ++mm) {
        int m = m0 + mm * 32;
        int b = bx * 64 + m;
        float sv = seq[(size_t)b * T + t];
        float pre[4];
#pragma unroll
        for (int q = 0; q < 4; ++q)
            pre[q] = gates[0][m][q * 16 + cc] + gates[1][m][q * 16 + cc]
                   + sv * wib[q] + bb[q];
        float ig = 1.0f / (1.0f + expf(-pre[0]));
        float fg = 1.0f / (1.0f + expf(-pre[1]));
        float gg = tanhf(pre[2]);
        float og = 1.0f / (1.0f + expf(-pre[3]));
        size_t ci = (size_t)b * H + kcol;
        float cn = fg * cbuf[ci] + ig * gg;
        cbuf[ci] = cn;
        float hv = og * tanhf(cn);
        u16 hb = f2bf(hv);
        hoh[ci] = hb;
        hol[ci] = f2bf(hv - bf2f(hb));
    }
}

// ---------------------------------------------------------------------------
// MLP head
// ---------------------------------------------------------------------------
__global__ __launch_bounds__(256) void head_kernel(const u16* __restrict__ hhi,
                                                   const u16* __restrict__ hlo,
                                                   const float* __restrict__ fc1w,
                                                   const float* __restrict__ fc1b,
                                                   const float* __restrict__ fc2w,
                                                   const float* __restrict__ fc2b,
                                                   float* __restrict__ out) {
    const int b = blockIdx.x;
    const int tid = threadIdx.x;
    __shared__ __align__(16) float hb[H];
    __shared__ float z[256];

    hb[tid]       = bf2f(hhi[(size_t)b * H + tid])       + bf2f(hlo[(size_t)b * H + tid]);
    hb[tid + 256] = bf2f(hhi[(size_t)b * H + tid + 256]) + bf2f(hlo[(size_t)b * H + tid + 256]);
    __syncthreads();

    float acc = fc1b[tid];
    const float4* wr = (const float4*)(fc1w + (size_t)tid * H);
    const float4* hr = (const float4*)hb;
#pragma unroll 4
    for (int kk = 0; kk < H / 4; ++kk) {
        float4 wv = wr[kk], hv = hr[kk];
        acc += wv.x * hv.x + wv.y * hv.y + wv.z * hv.z + wv.w * hv.w;
    }
    z[tid] = fmaxf(acc, 0.0f);
    __syncthreads();

    if (tid < TGT) {
        float a = fc2b[tid];
        const float* w2 = fc2w + (size_t)tid * 256;
#pragma unroll 8
        for (int j = 0; j < 256; ++j) a += z[j] * w2[j];
        out[(size_t)b * TGT + tid] = a;
    }
}

extern "C" void kernel_launch(void* const* d_in, const int* in_sizes, int n_in,
                              void* d_out, int out_size, void* d_ws, size_t ws_size,
                              hipStream_t stream) {
    const float* seq  = (const float*)d_in[0];
    const float* Wih  = (const float*)d_in[1];
    const float* Whh  = (const float*)d_in[2];
    const float* bih  = (const float*)d_in[3];
    const float* bhh  = (const float*)d_in[4];
    const float* fc1w = (const float*)d_in[5];
    const float* fc1b = (const float*)d_in[6];
    const float* fc2w = (const float*)d_in[7];
    const float* fc2b = (const float*)d_in[8];
    float* out = (float*)d_out;

    char* wsb = (char*)d_ws;
    u16*   wph  = (u16*)(wsb + OFF_WPH);
    u16*   wpl  = (u16*)(wsb + OFF_WPL);
    u16*   hhi0 = (u16*)(wsb + OFF_HHI0);
    u16*   hlo0 = (u16*)(wsb + OFF_HLO0);
    u16*   hhi1 = (u16*)(wsb + OFF_HHI1);
    u16*   hlo1 = (u16*)(wsb + OFF_HLO1);
    float* cbuf = (float*)(wsb + OFF_C);
    float* bias = (float*)(wsb + OFF_BIAS);

    init_pack<<<512, 256, 0, stream>>>(Whh, wph, wpl);
    init_state<<<2056, 256, 0, stream>>>((unsigned*)(wsb + OFF_HHI0), bias, bih, bhh);

    for (int t = 0; t < T; ++t) {
        const u16* ihi = (t & 1) ? hhi1 : hhi0;
        const u16* ilo = (t & 1) ? hlo1 : hlo0;
        u16* ohi = (t & 1) ? hhi0 : hhi1;
        u16* olo = (t & 1) ? hlo0 : hlo1;
        lstm_step<<<dim3(8, 32), 512, 0, stream>>>(wph, wpl, ihi, ilo, ohi, olo,
                                                   cbuf, bias, Wih, seq, t);
    }
    // T even -> final h in buffer 0
    head_kernel<<<B, 256, 0, stream>>>(hhi0, hlo0, fc1w, fc1b, fc2w, fc2b, out);
}

// Round 5
// 5249.464 us; speedup vs baseline: 7.5256x; 1.1499x over previous
//
#include <hip/hip_runtime.h>
#include <math.h>

#define H   512
#define B   512
#define T   512
#define TGT 28

typedef __bf16 bf16x8 __attribute__((ext_vector_type(8)));
typedef float  f32x4  __attribute__((ext_vector_type(4)));
typedef unsigned short u16;

// ws byte offsets
#define OFF_WPH  0x000000u  // Wpack_hi 2MB (frag-linear bf16)
#define OFF_WPL  0x200000u  // Wpack_lo 2MB
#define OFF_HHI0 0x400000u  // 512KB h hi buf0   (zeroed)
#define OFF_HLO0 0x480000u  // 512KB h lo buf0   (zeroed)
#define OFF_SYNC 0x500000u  // 4KB   sync page   (zeroed)
#define OFF_HHI1 0x501000u  // 512KB h hi buf1
#define OFF_HLO1 0x581000u  // 512KB h lo buf1

// LDS: W hi 64KB + W lo 64KB + gates[64][68] f32 (17408B) = 148480B -> 1 WG/CU
#define SMEM_BYTES (131072 + 64 * 68 * 4)

__device__ inline u16 f2bf(float x) {
    unsigned u = __builtin_bit_cast(unsigned, x);
    u += 0x7FFFu + ((u >> 16) & 1u);          // RNE
    return (u16)(u >> 16);
}
__device__ inline float bf2f(u16 h) {
    unsigned u = ((unsigned)h) << 16;
    return __builtin_bit_cast(float, u);
}

// ---------------------------------------------------------------------------
// Pack W_hh frag-linear bf16 hi/lo.  idx: r(5)|q(2)|S(4)|l(6), 8 k each.
// g = q*512 + r*16 + (l&15) ; k = S*32 + (l>>4)*8
// ---------------------------------------------------------------------------
__global__ __launch_bounds__(256) void init_pack(const float* __restrict__ Whh,
                                                 u16* __restrict__ wph,
                                                 u16* __restrict__ wpl) {
    int idx = blockIdx.x * 256 + threadIdx.x;   // [0, 131072)
    int l  = idx & 63;
    int S  = (idx >> 6) & 15;
    int q  = (idx >> 10) & 3;
    int r  = idx >> 12;
    int g  = q * 512 + r * 16 + (l & 15);
    int k  = S * 32 + ((l >> 4) * 8);
    const float* src = Whh + (size_t)g * H + k;
    __align__(16) u16 hi8[8];
    __align__(16) u16 lo8[8];
#pragma unroll
    for (int j = 0; j < 8; ++j) {
        float w = src[j];
        u16 hb = f2bf(w);
        hi8[j] = hb;
        lo8[j] = f2bf(w - bf2f(hb));
    }
    *(uint4*)(wph + (size_t)idx * 8) = *(const uint4*)hi8;
    *(uint4*)(wpl + (size_t)idx * 8) = *(const uint4*)lo8;
}

// zero [OFF_HHI0, OFF_HHI1) = h buf0 hi/lo + sync page = 263168 dwords
__global__ __launch_bounds__(256) void init_state(unsigned* __restrict__ zbase) {
    int idx = blockIdx.x * 256 + threadIdx.x;
    if (idx < 263168) zbase[idx] = 0u;
}

// ---------------------------------------------------------------------------
// Persistent XCD-local LSTM. 256 WGs x 512 thr, cooperative, 1 WG/CU.
// XCD p owns batch rows [p*64, p*64+64). Worker r (0..31) owns gate-cols
// {q*512 + r*16 .. +16}. W slice in LDS. c/Wih/bias in registers.
// Cross-CU h exchange through the XCD's own L2:
//   release: s_waitcnt vmcnt(0) (L1 is write-through -> stores in local L2)
//   arrive/spin: relaxed agent atomics (no fence -> no buffer_wbl2!)
//   acquire: buffer_inv sc0 (L1-only invalidate)
// ---------------------------------------------------------------------------
__global__ __launch_bounds__(512, 1) void lstm_persistent(
    const u16* __restrict__ wph, const u16* __restrict__ wpl,
    u16* __restrict__ hhi0, u16* __restrict__ hlo0,
    u16* __restrict__ hhi1, u16* __restrict__ hlo1,
    int* __restrict__ sync, const float* __restrict__ seq,
    const float* __restrict__ Wih, const float* __restrict__ bih,
    const float* __restrict__ bhh)
{
    extern __shared__ char smem[];
    u16* wh = (u16*)smem;                         // 64KB
    u16* wl = wh + 32768;                         // 64KB
    float (*gates)[68] = (float(*)[68])(smem + 131072);

    const int tid  = threadIdx.x;
    const int l    = tid & 63;
    const int wave = tid >> 6;
    const int mt   = wave & 1;
    const int kh   = wave >> 1;                   // 0..3

    // ---- partition assignment: physical XCD id + per-XCD slot ----
    __shared__ int sh_pr[2];
    if (tid == 0) {
        unsigned xcc;
        asm volatile("s_getreg_b32 %0, hwreg(HW_REG_XCC_ID)" : "=s"(xcc));
        int p = (int)(xcc & 7u);
        int r = __hip_atomic_fetch_add(&sync[p * 32], 1,
                                       __ATOMIC_RELAXED, __HIP_MEMORY_SCOPE_AGENT);
        sh_pr[0] = p;
        sh_pr[1] = r;                             // 0..31 (pigeonhole: 1 WG/CU)
    }
    __syncthreads();
    const int p = sh_pr[0];
    const int r = sh_pr[1];
    int* arrp = &sync[256 + p * 32];              // arrival counter, own line

    // ---- stage W slice (worker r) into LDS, once ----
    {
        const uint4* gh = (const uint4*)(wph + (size_t)r * 32768);
        const uint4* gl = (const uint4*)(wpl + (size_t)r * 32768);
        uint4* sh = (uint4*)wh;
        uint4* sl = (uint4*)wl;
#pragma unroll
        for (int i = 0; i < 8; ++i) {
            int idx = tid + i * 512;              // 0..4095
            sh[idx] = gh[idx];
            sl[idx] = gl[idx];
        }
    }

    // ---- thread-resident cell constants ----
    const int cc   = tid & 15;
    const int m0   = tid >> 4;                    // 0..31
    const int kcol = r * 16 + cc;
    float wib[4], bb[4];
#pragma unroll
    for (int q = 0; q < 4; ++q) {
        int g = q * 512 + kcol;
        wib[q] = Wih[g];
        bb[q]  = bih[g] + bhh[g];
    }
    float cr0 = 0.0f, cr1 = 0.0f;
    const int pb = p * 64;                        // partition batch base
    const int b0 = pb + m0;
    const int b1 = b0 + 32;

    const int arow0 = (pb + mt * 32 + (l & 15)) * H;
    const int arow1 = arow0 + 16 * H;

    __syncthreads();                              // W staged

    for (int t = 0; t < T; ++t) {
        const u16* hih = (t & 1) ? hhi1 : hhi0;
        const u16* hil = (t & 1) ? hlo1 : hlo0;
        u16* hoh = (t & 1) ? hhi0 : hhi1;
        u16* hol = (t & 1) ? hlo0 : hlo1;

        f32x4 acc[2][4] = {};

#pragma unroll
        for (int s = 0; s < 4; ++s) {
            const int S  = kh * 4 + s;
            const int ka = S * 32 + ((l >> 4) * 8);
            bf16x8 a0h = *(const bf16x8*)(hih + arow0 + ka);
            bf16x8 a1h = *(const bf16x8*)(hih + arow1 + ka);
            bf16x8 a0l = *(const bf16x8*)(hil + arow0 + ka);
            bf16x8 a1l = *(const bf16x8*)(hil + arow1 + ka);
#pragma unroll
            for (int n = 0; n < 4; ++n) {
                const int fo = ((n * 16 + S) * 64 + l) * 8;
                bf16x8 bh = *(const bf16x8*)(wh + fo);
                bf16x8 bl = *(const bf16x8*)(wl + fo);
                acc[0][n] = __builtin_amdgcn_mfma_f32_16x16x32_bf16(a0h, bh, acc[0][n], 0, 0, 0);
                acc[1][n] = __builtin_amdgcn_mfma_f32_16x16x32_bf16(a1h, bh, acc[1][n], 0, 0, 0);
                acc[0][n] = __builtin_amdgcn_mfma_f32_16x16x32_bf16(a0h, bl, acc[0][n], 0, 0, 0);
                acc[1][n] = __builtin_amdgcn_mfma_f32_16x16x32_bf16(a1h, bl, acc[1][n], 0, 0, 0);
                acc[0][n] = __builtin_amdgcn_mfma_f32_16x16x32_bf16(a0l, bh, acc[0][n], 0, 0, 0);
                acc[1][n] = __builtin_amdgcn_mfma_f32_16x16x32_bf16(a1l, bh, acc[1][n], 0, 0, 0);
            }
        }

        // ---- K reduction, 4 serialized rounds. D: col=lane&15, row=(lane>>4)*4+reg ----
#pragma unroll
        for (int rr = 0; rr < 4; ++rr) {
            if (kh == rr) {
#pragma unroll
                for (int ms = 0; ms < 2; ++ms)
#pragma unroll
                    for (int n = 0; n < 4; ++n)
#pragma unroll
                        for (int reg = 0; reg < 4; ++reg) {
                            int m  = mt * 32 + ms * 16 + (l >> 4) * 4 + reg;
                            int n2 = n * 16 + (l & 15);
                            if (rr == 0) gates[m][n2] = acc[ms][n][reg];
                            else         gates[m][n2] += acc[ms][n][reg];
                        }
            }
            __syncthreads();
        }

        // ---- cell update: 2 cells/thread, c in registers ----
        {
            float sv = seq[(size_t)b0 * T + t];
            float pre[4];
#pragma unroll
            for (int q = 0; q < 4; ++q) pre[q] = gates[m0][q * 16 + cc] + sv * wib[q] + bb[q];
            float ig = 1.0f / (1.0f + expf(-pre[0]));
            float fg = 1.0f / (1.0f + expf(-pre[1]));
            float gg = tanhf(pre[2]);
            float og = 1.0f / (1.0f + expf(-pre[3]));
            cr0 = fg * cr0 + ig * gg;
            float hv = og * tanhf(cr0);
            u16 hb = f2bf(hv);
            size_t ci = (size_t)b0 * H + kcol;
            hoh[ci] = hb;
            hol[ci] = f2bf(hv - bf2f(hb));
        }
        {
            float sv = seq[(size_t)b1 * T + t];
            float pre[4];
#pragma unroll
            for (int q = 0; q < 4; ++q) pre[q] = gates[m0 + 32][q * 16 + cc] + sv * wib[q] + bb[q];
            float ig = 1.0f / (1.0f + expf(-pre[0]));
            float fg = 1.0f / (1.0f + expf(-pre[1]));
            float gg = tanhf(pre[2]);
            float og = 1.0f / (1.0f + expf(-pre[3]));
            cr1 = fg * cr1 + ig * gg;
            float hv = og * tanhf(cr1);
            u16 hb = f2bf(hv);
            size_t ci = (size_t)b1 * H + kcol;
            hoh[ci] = hb;
            hol[ci] = f2bf(hv - bf2f(hb));
        }

        // ---- XCD-local barrier (skip after last step) ----
        if (t < T - 1) {
            asm volatile("s_waitcnt vmcnt(0)" ::: "memory");  // h stores in local L2
            __syncthreads();
            if (tid == 0) {
                __hip_atomic_fetch_add(arrp, 1, __ATOMIC_RELAXED,
                                       __HIP_MEMORY_SCOPE_AGENT);
                int target = 32 * (t + 1);
                while (__hip_atomic_load(arrp, __ATOMIC_RELAXED,
                                         __HIP_MEMORY_SCOPE_AGENT) < target)
                    __builtin_amdgcn_s_sleep(1);
            }
            __syncthreads();
            asm volatile("buffer_inv sc0" ::: "memory");      // invalidate L1 only
        }
    }
}

// ---------------------------------------------------------------------------
// MLP head
// ---------------------------------------------------------------------------
__global__ __launch_bounds__(256) void head_kernel(const u16* __restrict__ hhi,
                                                   const u16* __restrict__ hlo,
                                                   const float* __restrict__ fc1w,
                                                   const float* __restrict__ fc1b,
                                                   const float* __restrict__ fc2w,
                                                   const float* __restrict__ fc2b,
                                                   float* __restrict__ out) {
    const int b = blockIdx.x;
    const int tid = threadIdx.x;
    __shared__ __align__(16) float hb[H];
    __shared__ float z[256];

    hb[tid]       = bf2f(hhi[(size_t)b * H + tid])       + bf2f(hlo[(size_t)b * H + tid]);
    hb[tid + 256] = bf2f(hhi[(size_t)b * H + tid + 256]) + bf2f(hlo[(size_t)b * H + tid + 256]);
    __syncthreads();

    float acc = fc1b[tid];
    const float4* wr = (const float4*)(fc1w + (size_t)tid * H);
    const float4* hr = (const float4*)hb;
#pragma unroll 4
    for (int kk = 0; kk < H / 4; ++kk) {
        float4 wv = wr[kk], hv = hr[kk];
        acc += wv.x * hv.x + wv.y * hv.y + wv.z * hv.z + wv.w * hv.w;
    }
    z[tid] = fmaxf(acc, 0.0f);
    __syncthreads();

    if (tid < TGT) {
        float a = fc2b[tid];
        const float* w2 = fc2w + (size_t)tid * 256;
#pragma unroll 8
        for (int j = 0; j < 256; ++j) a += z[j] * w2[j];
        out[(size_t)b * TGT + tid] = a;
    }
}

extern "C" void kernel_launch(void* const* d_in, const int* in_sizes, int n_in,
                              void* d_out, int out_size, void* d_ws, size_t ws_size,
                              hipStream_t stream) {
    const float* seq  = (const float*)d_in[0];
    const float* Wih  = (const float*)d_in[1];
    const float* Whh  = (const float*)d_in[2];
    const float* bih  = (const float*)d_in[3];
    const float* bhh  = (const float*)d_in[4];
    const float* fc1w = (const float*)d_in[5];
    const float* fc1b = (const float*)d_in[6];
    const float* fc2w = (const float*)d_in[7];
    const float* fc2b = (const float*)d_in[8];
    float* out = (float*)d_out;

    char* wsb = (char*)d_ws;
    u16* wph  = (u16*)(wsb + OFF_WPH);
    u16* wpl  = (u16*)(wsb + OFF_WPL);
    u16* hhi0 = (u16*)(wsb + OFF_HHI0);
    u16* hlo0 = (u16*)(wsb + OFF_HLO0);
    u16* hhi1 = (u16*)(wsb + OFF_HHI1);
    u16* hlo1 = (u16*)(wsb + OFF_HLO1);
    int* sync = (int*)(wsb + OFF_SYNC);

    init_pack<<<512, 256, 0, stream>>>(Whh, wph, wpl);
    init_state<<<1028, 256, 0, stream>>>((unsigned*)(wsb + OFF_HHI0));

    hipFuncSetAttribute((const void*)lstm_persistent,
                        hipFuncAttributeMaxDynamicSharedMemorySize, SMEM_BYTES);

    void* args[] = {(void*)&wph, (void*)&wpl, (void*)&hhi0, (void*)&hlo0,
                    (void*)&hhi1, (void*)&hlo1, (void*)&sync, (void*)&seq,
                    (void*)&Wih, (void*)&bih, (void*)&bhh};
    hipLaunchCooperativeKernel((const void*)lstm_persistent, dim3(256), dim3(512),
                               args, SMEM_BYTES, stream);

    // T even -> final h in buffer 0
    head_kernel<<<B, 256, 0, stream>>>(hhi0, hlo0, fc1w, fc1b, fc2w, fc2b, out);
}